// Round 9
// baseline (266.466 us; speedup 1.0000x reference)
//
#include <hip/hip_runtime.h>
#include <hip/hip_bf16.h>
#include <cstdint>
#include <cstddef>

#define NTOK 8192
#define DIM  1024
#define NEXP 64
#define RANK 64
#define NGRP 8
#define NLOC 8
#define ECAP 2048   // per-expert bucket capacity (expected ~256, 8x margin)

typedef __attribute__((ext_vector_type(8))) short bf16x8;
typedef __attribute__((ext_vector_type(4))) float f32x4;

static __device__ inline unsigned int pack_bf16x2(float a, float b) {
    __hip_bfloat16 ha = __float2bfloat16(a);
    __hip_bfloat16 hb = __float2bfloat16(b);
    return (unsigned int)(*(unsigned short*)&ha) |
           ((unsigned int)(*(unsigned short*)&hb) << 16);
}

// ---------------------------------------------------------------------------
// score_all: dense fp32 GEMM  S[8192][72] = h @ [Wg | Wloc_g0..g7].
// FP-ORDER CONTRACT (round-5 failure): per token+column, accumulation is
// serial over k ascending within each k-half (z=2); halves added pairwise in
// route_all — EXACTLY the verified order. b values are bitwise copies (Wt is
// a pure transpose), FMA sequence identical to round 8 -> scores bitwise eq.
// Round-8 post-mortem: 9 LDS instr per 40 FMAs; per-CU LDS pipe ~420cy/kq
// vs VALU 160cy -> LDS-pipe bound at 2 waves/SIMD. Fix: weight reads moved
// OFF the LDS pipe — uniform float4 loads from pre-transposed fp32
// Wt[72][1024] (global, L2-resident, 1 broadcast transaction/wave on the
// idle VMEM pipe). LDS now carries only the conflict-free h a-reads (4/kq).
// ---------------------------------------------------------------------------
__global__ __launch_bounds__(512) void score_all(
    const float* __restrict__ h, const float* __restrict__ Wt,
    unsigned short* __restrict__ hb, float* __restrict__ Sp)
{
    __shared__ float Hs[128][66];  // [token][k], pad 66: b64 reads 2-way (free)

    const int tile = blockIdx.x;          // 0..63 (128 tokens)
    const int slab = blockIdx.y;          // 0: cols 0..39   1: cols 40..71
    const int z    = blockIdx.z;          // k half (ORDER-LOCKED: must stay 2)
    const int tid  = threadIdx.x;
    const int wave = tid >> 6;            // 0..7
    const int lane = tid & 63;
    const int t0   = tile * 128;
    const int kz   = z * 512;

    const int r0  = tid >> 2;             // 0..127 (staging row)
    const int seg = (tid & 3) * 16;       // 0,16,32,48

    const int c0g = slab ? (40 + wave * 4) : (wave * 5);  // global col base
    const float* wt0 = Wt + (size_t)c0g * 1024;

    float acc[10] = {};                   // [token0 c<5 | token1 at 5+c]

    float4 hpre[4];
    {   // prologue: h chunk 0
        const float* src = h + (size_t)(t0 + r0) * DIM + kz + seg;
        hpre[0] = *(const float4*)(src);
        hpre[1] = *(const float4*)(src + 4);
        hpre[2] = *(const float4*)(src + 8);
        hpre[3] = *(const float4*)(src + 12);
    }

    for (int chunk = 0; chunk < 8; ++chunk) {
        const int kb = kz + chunk * 64;

        // ---- write staged regs -> LDS (+ fused hb cast on slab 0) ----
        {
            float* dst = &Hs[r0][seg];
#pragma unroll
            for (int q = 0; q < 4; ++q) {
                const float4 v = hpre[q];
                *(float2*)(dst + q * 4)     = make_float2(v.x, v.y);
                *(float2*)(dst + q * 4 + 2) = make_float2(v.z, v.w);
            }
            if (slab == 0) {
                unsigned short* hrow = hb + (size_t)(t0 + r0) * DIM + kb + seg;
#pragma unroll
                for (int q = 0; q < 4; ++q) {
                    const float4 v = hpre[q];
                    uint2 pk;
                    pk.x = pack_bf16x2(v.x, v.y);
                    pk.y = pack_bf16x2(v.z, v.w);
                    *(uint2*)(hrow + q * 4) = pk;
                }
            }
        }
        __syncthreads();

        // ---- prefetch next h chunk (flies during compute) ----
        if (chunk < 7) {
            const float* src = h + (size_t)(t0 + r0) * DIM + kb + 64 + seg;
            hpre[0] = *(const float4*)(src);
            hpre[1] = *(const float4*)(src + 4);
            hpre[2] = *(const float4*)(src + 8);
            hpre[3] = *(const float4*)(src + 12);
        }

        // ---- compute: lane = 2 tokens (t0+lane, t0+64+lane), wave = cols ----
        // Per acc[c]: k strictly ascending (x,y,z,w per quad) == verified order.
        if (slab == 0) {
#pragma unroll 4
            for (int kq = 0; kq < 16; ++kq) {
                const int k0 = kq * 4;
                const float* wtk = wt0 + kb + k0;
                float4 bq[5];
#pragma unroll
                for (int c = 0; c < 5; ++c)
                    bq[c] = *(const float4*)(wtk + (size_t)c * 1024);
                const float2 a00 = *(const float2*)&Hs[lane][k0];
                const float2 a01 = *(const float2*)&Hs[lane][k0 + 2];
                const float2 a10 = *(const float2*)&Hs[64 + lane][k0];
                const float2 a11 = *(const float2*)&Hs[64 + lane][k0 + 2];
#pragma unroll
                for (int c = 0; c < 5; ++c) {
                    acc[c] += a00.x * bq[c].x; acc[5 + c] += a10.x * bq[c].x;
                }
#pragma unroll
                for (int c = 0; c < 5; ++c) {
                    acc[c] += a00.y * bq[c].y; acc[5 + c] += a10.y * bq[c].y;
                }
#pragma unroll
                for (int c = 0; c < 5; ++c) {
                    acc[c] += a01.x * bq[c].z; acc[5 + c] += a11.x * bq[c].z;
                }
#pragma unroll
                for (int c = 0; c < 5; ++c) {
                    acc[c] += a01.y * bq[c].w; acc[5 + c] += a11.y * bq[c].w;
                }
            }
        } else {
#pragma unroll 4
            for (int kq = 0; kq < 16; ++kq) {
                const int k0 = kq * 4;
                const float* wtk = wt0 + kb + k0;
                float4 bq[4];
#pragma unroll
                for (int c = 0; c < 4; ++c)
                    bq[c] = *(const float4*)(wtk + (size_t)c * 1024);
                const float2 a00 = *(const float2*)&Hs[lane][k0];
                const float2 a01 = *(const float2*)&Hs[lane][k0 + 2];
                const float2 a10 = *(const float2*)&Hs[64 + lane][k0];
                const float2 a11 = *(const float2*)&Hs[64 + lane][k0 + 2];
#pragma unroll
                for (int c = 0; c < 4; ++c) {
                    acc[c] += a00.x * bq[c].x; acc[5 + c] += a10.x * bq[c].x;
                }
#pragma unroll
                for (int c = 0; c < 4; ++c) {
                    acc[c] += a00.y * bq[c].y; acc[5 + c] += a10.y * bq[c].y;
                }
#pragma unroll
                for (int c = 0; c < 4; ++c) {
                    acc[c] += a01.x * bq[c].z; acc[5 + c] += a11.x * bq[c].z;
                }
#pragma unroll
                for (int c = 0; c < 4; ++c) {
                    acc[c] += a01.y * bq[c].w; acc[5 + c] += a11.y * bq[c].w;
                }
            }
        }
        __syncthreads();
    }

    // ---- write k-half partial scores (2 tokens per lane) ----
    const int nout = slab ? 4 : 5;
    float* dstS  = Sp + (size_t)z * (NTOK * 72) + (size_t)(t0 + lane) * 72 + c0g;
    float* dstS2 = Sp + (size_t)z * (NTOK * 72) + (size_t)(t0 + 64 + lane) * 72 + c0g;
#pragma unroll
    for (int c = 0; c < 5; ++c) {
        if (c < nout) {
            dstS[c]  = acc[c];
            dstS2[c] = acc[5 + c];
        }
    }
}

// ---------------------------------------------------------------------------
// route_all: sum 2 k-half partials (verified order), group argmax (+bg),
// top-2 in selected group, softmax, outputs + DIRECT scatter into fixed-cap
// per-expert buckets (pos = atomic cursor; intra-bucket order arbitrary —
// verified benign). Replaces the separate scatter_e dispatch.
// ---------------------------------------------------------------------------
__global__ __launch_bounds__(256) void route_all(
    const float* __restrict__ Sp, const float* __restrict__ bg,
    float* __restrict__ out_gidx, float* __restrict__ out_eid,
    float* __restrict__ out_gate, int* __restrict__ cursor,
    int* __restrict__ token_list, float* __restrict__ slot_gate)
{
    const int t = blockIdx.x * 256 + threadIdx.x;
    const float* p0 = Sp + (size_t)t * 72;
    const float* p1 = p0 + (size_t)NTOK * 72;
    float s[72];
#pragma unroll
    for (int i = 0; i < 18; ++i) {
        const float4 a = *(const float4*)(p0 + i * 4);
        const float4 b = *(const float4*)(p1 + i * 4);
        s[i * 4 + 0] = a.x + b.x; s[i * 4 + 1] = a.y + b.y;
        s[i * 4 + 2] = a.z + b.z; s[i * 4 + 3] = a.w + b.w;
    }

    int gi = 0; float best = s[0] + bg[0];
#pragma unroll
    for (int g = 1; g < NGRP; ++g) {
        const float v = s[g] + bg[g];
        if (v > best) { best = v; gi = g; }
    }

    float ls[NLOC];
#pragma unroll
    for (int m = 0; m < NLOC; ++m) ls[m] = s[8 + gi * NLOC + m];

    int m1 = 0; float v1 = ls[0];
#pragma unroll
    for (int m = 1; m < NLOC; ++m) { if (ls[m] > v1) { v1 = ls[m]; m1 = m; } }
    int m2 = (m1 == 0) ? 1 : 0; float v2 = ls[m2];
#pragma unroll
    for (int m = 0; m < NLOC; ++m) {
        if (m != m1 && m != ((m1 == 0) ? 1 : 0) && ls[m] > v2) { v2 = ls[m]; m2 = m; }
    }
    const float e2v = expf(v2 - v1);
    const float inv = 1.f / (1.f + e2v);
    const float g0 = inv, g1 = e2v * inv;
    const int ea = gi * NLOC + m1, eb = gi * NLOC + m2;

    out_gidx[t] = (float)gi;
    out_eid[t * 2 + 0] = (float)ea;
    out_eid[t * 2 + 1] = (float)eb;
    out_gate[t * 2 + 0] = g0;
    out_gate[t * 2 + 1] = g1;

    const int pA = atomicAdd(&cursor[ea], 1);
    if (pA < ECAP) {
        token_list[ea * ECAP + pA] = t * 2 + 0;
        slot_gate[ea * ECAP + pA] = g0;
    }
    const int pB = atomicAdd(&cursor[eb], 1);
    if (pB < ECAP) {
        token_list[eb * ECAP + pB] = t * 2 + 1;
        slot_gate[eb * ECAP + pB] = g1;
    }
}

// ---------------------------------------------------------------------------
// prep_w: W1/W2 transpose+cast (y<32) + Wt fp32 transpose build (y==32).
// Wt[72][1024]: col-major copy of [Wg | Wloc] — bitwise copies (score_all's
// b values identical to staging from the originals).
// ---------------------------------------------------------------------------
__global__ __launch_bounds__(256) void prep_w(
    const float* __restrict__ W1, const float* __restrict__ W2,
    const float* __restrict__ Wg, const float* __restrict__ Wloc,
    unsigned short* __restrict__ W1t, unsigned short* __restrict__ W2t,
    float* __restrict__ Wt)
{
    __shared__ float Ls[64][65];
    const int e = blockIdx.x;
    const int y = blockIdx.y;
    if (y == 32) {
        if (e < 36) {
#pragma unroll
            for (int cc = 0; cc < 2; ++cc) {
                const int c = e * 2 + cc;
                const float* src = (c < 8)
                    ? (Wg + c)
                    : (Wloc + (size_t)((c - 8) >> 3) * (DIM * NLOC) + ((c - 8) & 7));
                for (int k = threadIdx.x; k < DIM; k += 256)
                    Wt[(size_t)c * DIM + k] = src[(size_t)k * NLOC];
                // (Wg stride == NLOC == NGRP == 8 floats per k)
            }
        }
        return;
    }
    if (y < 16) {
        const int kb = y;
        const float* src = W1 + (size_t)e * DIM * RANK + (size_t)kb * 64 * RANK;
#pragma unroll
        for (int it = 0; it < 4; ++it) {
            const int kk = (threadIdx.x >> 4) + it * 16;
            const int rr = (threadIdx.x & 15) * 4;
            *(float4*)&Ls[kk][rr] = *(const float4*)(src + (size_t)kk * RANK + rr);
        }
        __syncthreads();
#pragma unroll
        for (int it = 0; it < 2; ++it) {
            const int idx = threadIdx.x + it * 256;
            const int r = idx >> 3, k8 = (idx & 7) * 8;
            uint4 v;
            v.x = pack_bf16x2(Ls[k8 + 0][r], Ls[k8 + 1][r]);
            v.y = pack_bf16x2(Ls[k8 + 2][r], Ls[k8 + 3][r]);
            v.z = pack_bf16x2(Ls[k8 + 4][r], Ls[k8 + 5][r]);
            v.w = pack_bf16x2(Ls[k8 + 6][r], Ls[k8 + 7][r]);
            *(uint4*)(W1t + (size_t)e * RANK * DIM + (size_t)r * DIM + kb * 64 + k8) = v;
        }
    } else {
        const int db = y - 16;
        const float* src = W2 + (size_t)e * RANK * DIM + db * 64;
#pragma unroll
        for (int it = 0; it < 4; ++it) {
            const int rr = (threadIdx.x >> 4) + it * 16;
            const int dd = (threadIdx.x & 15) * 4;
            *(float4*)&Ls[rr][dd] = *(const float4*)(src + (size_t)rr * DIM + dd);
        }
        __syncthreads();
#pragma unroll
        for (int it = 0; it < 2; ++it) {
            const int idx = threadIdx.x + it * 256;
            const int d = idx >> 3, r8 = (idx & 7) * 8;
            uint4 v;
            v.x = pack_bf16x2(Ls[r8 + 0][d], Ls[r8 + 1][d]);
            v.y = pack_bf16x2(Ls[r8 + 2][d], Ls[r8 + 3][d]);
            v.z = pack_bf16x2(Ls[r8 + 4][d], Ls[r8 + 5][d]);
            v.w = pack_bf16x2(Ls[r8 + 6][d], Ls[r8 + 7][d]);
            *(uint4*)(W2t + (size_t)e * DIM * RANK + (size_t)(db * 64 + d) * RANK + r8) = v;
        }
    }
}

// ---------------------------------------------------------------------------
// E1 (MFMA): P[slot][r] = bf16( gate * relu(h[tok] @ W1[e]) ).
// Fixed-cap buckets: base = e*ECAP, ne = cursor[e] (scan removed).
// ---------------------------------------------------------------------------
__global__ __launch_bounds__(256, 2) void e1_mfma(
    const unsigned short* __restrict__ hb, const unsigned short* __restrict__ W1t,
    const int* __restrict__ counts, const int* __restrict__ token_list,
    const float* __restrict__ slot_gate, unsigned short* __restrict__ P)
{
    __shared__ unsigned short Hs[64 * 72];
    __shared__ unsigned short Ws[64 * 72];
    __shared__ int   tokS[64];
    __shared__ float gateS[64];

    const int e   = blockIdx.x;
    const int tid = threadIdx.x;
    const int ne  = min(counts[e], ECAP);
    const int base = e * ECAP;

    const unsigned short* W1te = W1t + (size_t)e * RANK * DIM;
    const int wave = tid >> 6;
    const int lane = tid & 63;
    const int tx   = lane & 15;
    const int quad = lane >> 4;

    for (int tile = blockIdx.y; tile * 64 < ne; tile += 8) {
        const int row0 = tile * 64;
        __syncthreads();
        if (tid < 64) {
            const int gr = row0 + tid;
            tokS[tid]  = (gr < ne) ? token_list[base + gr] : -1;
            gateS[tid] = (gr < ne) ? slot_gate[base + gr] : 0.f;
        }
        f32x4 acc[4] = {};
        for (int kc = 0; kc < DIM; kc += 64) {
            __syncthreads();
#pragma unroll
            for (int it = 0; it < 2; ++it) {
                const int idx = tid + it * 256;
                const int s = idx >> 3, k8 = (idx & 7) * 8;
                const int ent = tokS[s];
                uint4 v = make_uint4(0, 0, 0, 0);
                if (ent >= 0)
                    v = *(const uint4*)(hb + (size_t)(ent >> 1) * DIM + kc + k8);
                *(uint4*)(Hs + s * 72 + k8) = v;
            }
#pragma unroll
            for (int it = 0; it < 2; ++it) {
                const int idx = tid + it * 256;
                const int r = idx >> 3, k8 = (idx & 7) * 8;
                *(uint4*)(Ws + r * 72 + k8) =
                    *(const uint4*)(W1te + (size_t)r * DIM + kc + k8);
            }
            __syncthreads();
#pragma unroll
            for (int ks = 0; ks < 2; ++ks) {
                const bf16x8 a = *(const bf16x8*)(Hs + (wave * 16 + tx) * 72 + ks * 32 + quad * 8);
#pragma unroll
                for (int j = 0; j < 4; ++j) {
                    const bf16x8 b = *(const bf16x8*)(Ws + (j * 16 + tx) * 72 + ks * 32 + quad * 8);
                    acc[j] = __builtin_amdgcn_mfma_f32_16x16x32_bf16(a, b, acc[j], 0, 0, 0);
                }
            }
        }
#pragma unroll
        for (int j = 0; j < 4; ++j) {
#pragma unroll
            for (int i = 0; i < 4; ++i) {
                const int sl = wave * 16 + quad * 4 + i;
                const int gr = row0 + sl;
                if (gr < ne) {
                    const float v = fmaxf(acc[j][i], 0.f) * gateS[sl];
                    __hip_bfloat16 hv = __float2bfloat16(v);
                    P[(size_t)(base + gr) * RANK + j * 16 + tx] = *(unsigned short*)&hv;
                }
            }
        }
    }
}

// ---------------------------------------------------------------------------
// E2 (MFMA): C = P[slot] @ W2[e]; j=0 -> out[tok], j=1 -> contrib[tok].
// Round-7 lesson: fp32 atomicAdd RMW 2-3x slower than streaming stores.
// ---------------------------------------------------------------------------
__global__ __launch_bounds__(256, 2) void e2_mfma(
    const unsigned short* __restrict__ P, const unsigned short* __restrict__ W2t,
    const int* __restrict__ counts, const int* __restrict__ token_list,
    float* __restrict__ out, float* __restrict__ contrib)
{
    __shared__ unsigned short Ps[64 * 72];
    __shared__ unsigned short W2s[64 * 72];
    __shared__ int tokS[64];

    const int e = blockIdx.x;
    const int colbase = blockIdx.y * 64;
    const int tid = threadIdx.x;
    const int ne  = min(counts[e], ECAP);
    const int base = e * ECAP;

    const unsigned short* W2te = W2t + (size_t)e * DIM * RANK;
    const int wave = tid >> 6;
    const int lane = tid & 63;
    const int tx   = lane & 15;
    const int quad = lane >> 4;

#pragma unroll
    for (int it = 0; it < 2; ++it) {
        const int idx = tid + it * 256;
        const int d = idx >> 3, r8 = (idx & 7) * 8;
        *(uint4*)(W2s + d * 72 + r8) =
            *(const uint4*)(W2te + (size_t)(colbase + d) * RANK + r8);
    }

    for (int tile = blockIdx.z; tile * 64 < ne; tile += 4) {
        const int row0 = tile * 64;
        __syncthreads();
        if (tid < 64) {
            const int gr = row0 + tid;
            tokS[tid] = (gr < ne) ? token_list[base + gr] : -1;
        }
#pragma unroll
        for (int it = 0; it < 2; ++it) {
            const int idx = tid + it * 256;
            const int s = idx >> 3, r8 = (idx & 7) * 8;
            const int gr = row0 + s;
            uint4 v = make_uint4(0, 0, 0, 0);
            if (gr < ne) v = *(const uint4*)(P + (size_t)(base + gr) * RANK + r8);
            *(uint4*)(Ps + s * 72 + r8) = v;
        }
        __syncthreads();
        f32x4 acc[4] = {};
#pragma unroll
        for (int ks = 0; ks < 2; ++ks) {
            const bf16x8 a = *(const bf16x8*)(Ps + (wave * 16 + tx) * 72 + ks * 32 + quad * 8);
#pragma unroll
            for (int j = 0; j < 4; ++j) {
                const bf16x8 b = *(const bf16x8*)(W2s + (j * 16 + tx) * 72 + ks * 32 + quad * 8);
                acc[j] = __builtin_amdgcn_mfma_f32_16x16x32_bf16(a, b, acc[j], 0, 0, 0);
            }
        }
#pragma unroll
        for (int i = 0; i < 4; ++i) {
            const int sl = wave * 16 + quad * 4 + i;
            const int ent = tokS[sl];
            if (ent >= 0) {
                float* basep = (ent & 1) ? contrib : out;
                float* op = basep + (size_t)(ent >> 1) * DIM + colbase;
#pragma unroll
                for (int j = 0; j < 4; ++j)
                    op[j * 16 + tx] = acc[j][i];
            }
        }
    }
}

// ---------------------------------------------------------------------------
__global__ __launch_bounds__(256) void combine_kernel(
    const float* __restrict__ contrib, float* __restrict__ out)
{
    const size_t i = (size_t)blockIdx.x * 256 + threadIdx.x;
    float4 a = ((const float4*)out)[i];
    const float4 b = ((const float4*)contrib)[i];
    a.x += b.x; a.y += b.y; a.z += b.z; a.w += b.w;
    ((float4*)out)[i] = a;
}

// ---------------------------------------------------------------------------
extern "C" void kernel_launch(void* const* d_in, const int* in_sizes, int n_in,
                              void* d_out, int out_size, void* d_ws, size_t ws_size,
                              hipStream_t stream)
{
    const float* h    = (const float*)d_in[0];
    const float* Wg   = (const float*)d_in[1];
    const float* bg   = (const float*)d_in[2];
    const float* Wloc = (const float*)d_in[3];
    const float* W1   = (const float*)d_in[4];
    const float* W2   = (const float*)d_in[5];

    float* out_f    = (float*)d_out;
    float* out_main = out_f;
    float* out_eid  = out_f + (size_t)NTOK * DIM;
    float* out_gate = out_eid + (size_t)NTOK * 2;
    float* out_gidx = out_gate + (size_t)NTOK * 2;

    int* ws_i        = (int*)d_ws;
    int* cursor_e    = ws_i;                                  // 64 ints
    int* token_list  = ws_i + 1024;                           // 64*2048 ints
    float* slot_gate = (float*)(ws_i + 1024 + NEXP * ECAP);   // 64*2048 floats
    float* Sp        = slot_gate + NEXP * ECAP;               // 2*8192*72 floats
    float* Wt        = Sp + (size_t)2 * NTOK * 72;            // 72*1024 floats
    unsigned short* P_h = (unsigned short*)(Wt + 72 * DIM);   // 64*2048*64 bf16 (16.8 MB)
    unsigned short* W1t = P_h + (size_t)NEXP * ECAP * RANK;   // 8 MB
    unsigned short* W2t = W1t + (size_t)NEXP * RANK * DIM;    // 8 MB
    float* contrib      = (float*)(W2t + (size_t)NEXP * DIM * RANK);  // 33.5 MB
    // hb (16.8 MB) aliases contrib: written by score_all (slab 0), read by
    // e1, clobbered by e2's contrib stores (e1 complete by then;
    // stream-serial). Verified pattern from rounds 0-4/8.
    unsigned short* hb = (unsigned short*)contrib;

    hipMemsetAsync(cursor_e, 0, 64 * sizeof(int), stream);

    prep_w<<<dim3(NEXP, 33), 256, 0, stream>>>(W1, W2, Wg, Wloc, W1t, W2t, Wt);
    score_all<<<dim3(64, 2, 2), 512, 0, stream>>>(h, Wt, hb, Sp);
    route_all<<<NTOK / 256, 256, 0, stream>>>(Sp, bg, out_gidx, out_eid,
        out_gate, cursor_e, token_list, slot_gate);
    e1_mfma<<<dim3(NEXP, 8), 256, 0, stream>>>(hb, W1t, cursor_e, token_list,
        slot_gate, P_h);
    e2_mfma<<<dim3(NEXP, 16, 4), 256, 0, stream>>>(P_h, W2t, cursor_e, token_list,
        out_main, contrib);
    combine_kernel<<<(NTOK * DIM / 4) / 256, 256, 0, stream>>>(contrib, out_main);
}

// Round 10
// 239.211 us; speedup vs baseline: 1.1139x; 1.1139x over previous
//
#include <hip/hip_runtime.h>
#include <hip/hip_bf16.h>
#include <cstdint>
#include <cstddef>

#define NTOK 8192
#define DIM  1024
#define NEXP 64
#define RANK 64
#define NGRP 8
#define NLOC 8
#define ECAP 2048   // per-expert bucket capacity (expected ~256, 8x margin)

typedef __attribute__((ext_vector_type(8))) short bf16x8;
typedef __attribute__((ext_vector_type(4))) float f32x4;

static __device__ inline unsigned int pack_bf16x2(float a, float b) {
    __hip_bfloat16 ha = __float2bfloat16(a);
    __hip_bfloat16 hb = __float2bfloat16(b);
    return (unsigned int)(*(unsigned short*)&ha) |
           ((unsigned int)(*(unsigned short*)&hb) << 16);
}

// ---------------------------------------------------------------------------
// score_all: dense fp32 GEMM  S[8192][72] = h @ [Wg | Wloc_g0..g7].
// FP-ORDER CONTRACT (round-5 failure): per token+column, accumulation is
// serial over k ascending within each k-half (z=2); halves added pairwise in
// route_all — EXACTLY the verified order.
// Round-9 lesson (confirmed twice, r2/r3 and r9): shared weight operands MUST
// be staged in LDS once per block — uniform global reads of the same small
// buffer from all CUs serialize on L2 (50 -> 67us). This is the verified
// round-8 kernel: 512 threads (2 waves/SIMD), LDS Ws [col][k] uniform b128,
// register prefetch one chunk ahead. Scores bitwise = rounds 6/8.
// ---------------------------------------------------------------------------
__global__ __launch_bounds__(512) void score_all(
    const float* __restrict__ h, const float* __restrict__ Wg,
    const float* __restrict__ Wloc, unsigned short* __restrict__ hb,
    float* __restrict__ Sp)
{
    __shared__ float Hs[128][66];  // [token][k], pad 66: b64 reads (cheap)
    __shared__ float Ws[40][72];   // [col][k],  pad 72: uniform b128 broadcast

    const int tile = blockIdx.x;          // 0..63 (128 tokens)
    const int slab = blockIdx.y;          // 0: cols 0..39 (Wg,g0..3)  1: 40..71 (g4..7)
    const int z    = blockIdx.z;          // k half (ORDER-LOCKED: must stay 2)
    const int tid  = threadIdx.x;
    const int wave = tid >> 6;            // 0..7
    const int lane = tid & 63;
    const int t0   = tile * 128;
    const int kz   = z * 512;

    const int r0  = tid >> 2;             // 0..127 (staging row)
    const int seg = (tid & 3) * 16;       // 0,16,32,48

    float acc[10] = {};                   // [token0 c<5 | token1 at 5+c]

    float4 hpre[4];
    float4 wgp;          // slab 0, tid<128 only
    float4 wlp;

    {   // prologue: load chunk 0
        const int kb = kz;
        const float* src = h + (size_t)(t0 + r0) * DIM + kb + seg;
        hpre[0] = *(const float4*)(src);
        hpre[1] = *(const float4*)(src + 4);
        hpre[2] = *(const float4*)(src + 8);
        hpre[3] = *(const float4*)(src + 12);
        const int g = tid >> 7, r = tid & 127;
        if (slab == 0) {
            if (tid < 128)
                wgp = *(const float4*)(Wg + (size_t)(kb + (tid >> 1)) * NGRP + (tid & 1) * 4);
            wlp = *(const float4*)(Wloc + (size_t)g * (DIM * NLOC)
                                       + (size_t)(kb + (r >> 1)) * NLOC + (r & 1) * 4);
        } else {
            wlp = *(const float4*)(Wloc + (size_t)(4 + g) * (DIM * NLOC)
                                       + (size_t)(kb + (r >> 1)) * NLOC + (r & 1) * 4);
        }
    }

    for (int chunk = 0; chunk < 8; ++chunk) {
        const int kb = kz + chunk * 64;

        // ---- write staged regs -> LDS (+ fused hb cast on slab 0) ----
        {
            float* dst = &Hs[r0][seg];
#pragma unroll
            for (int q = 0; q < 4; ++q) {
                const float4 v = hpre[q];
                *(float2*)(dst + q * 4)     = make_float2(v.x, v.y);
                *(float2*)(dst + q * 4 + 2) = make_float2(v.z, v.w);
            }
            if (slab == 0) {
                unsigned short* hrow = hb + (size_t)(t0 + r0) * DIM + kb + seg;
#pragma unroll
                for (int q = 0; q < 4; ++q) {
                    const float4 v = hpre[q];
                    uint2 pk;
                    pk.x = pack_bf16x2(v.x, v.y);
                    pk.y = pack_bf16x2(v.z, v.w);
                    *(uint2*)(hrow + q * 4) = pk;
                }
            }
        }
        {
            const int g = tid >> 7, r = tid & 127;
            const int k = r >> 1;
            if (slab == 0) {
                if (tid < 128) {
                    const int kk = tid >> 1, m4 = (tid & 1) * 4;
                    Ws[m4 + 0][kk] = wgp.x; Ws[m4 + 1][kk] = wgp.y;
                    Ws[m4 + 2][kk] = wgp.z; Ws[m4 + 3][kk] = wgp.w;
                }
                const int c = 8 + g * 8 + (r & 1) * 4;
                Ws[c + 0][k] = wlp.x; Ws[c + 1][k] = wlp.y;
                Ws[c + 2][k] = wlp.z; Ws[c + 3][k] = wlp.w;
            } else {
                const int c = g * 8 + (r & 1) * 4;
                Ws[c + 0][k] = wlp.x; Ws[c + 1][k] = wlp.y;
                Ws[c + 2][k] = wlp.z; Ws[c + 3][k] = wlp.w;
            }
        }
        __syncthreads();

        // ---- prefetch chunk+1 (global loads overlap compute below) ----
        if (chunk < 7) {
            const int kbn = kb + 64;
            const float* src = h + (size_t)(t0 + r0) * DIM + kbn + seg;
            hpre[0] = *(const float4*)(src);
            hpre[1] = *(const float4*)(src + 4);
            hpre[2] = *(const float4*)(src + 8);
            hpre[3] = *(const float4*)(src + 12);
            const int g = tid >> 7, r = tid & 127;
            if (slab == 0) {
                if (tid < 128)
                    wgp = *(const float4*)(Wg + (size_t)(kbn + (tid >> 1)) * NGRP + (tid & 1) * 4);
                wlp = *(const float4*)(Wloc + (size_t)g * (DIM * NLOC)
                                           + (size_t)(kbn + (r >> 1)) * NLOC + (r & 1) * 4);
            } else {
                wlp = *(const float4*)(Wloc + (size_t)(4 + g) * (DIM * NLOC)
                                           + (size_t)(kbn + (r >> 1)) * NLOC + (r & 1) * 4);
            }
        }

        // ---- compute: lane = 2 tokens (t0+lane, t0+64+lane), wave = cols ----
        // Per acc[c]: k strictly ascending (x,y,z,w per quad) == verified order.
        if (slab == 0) {
            const int c0 = wave * 5;
#pragma unroll 2
            for (int kq = 0; kq < 16; ++kq) {
                const int k0 = kq * 4;
                const float2 a00 = *(const float2*)&Hs[lane][k0];
                const float2 a01 = *(const float2*)&Hs[lane][k0 + 2];
                const float2 a10 = *(const float2*)&Hs[64 + lane][k0];
                const float2 a11 = *(const float2*)&Hs[64 + lane][k0 + 2];
                float4 bq[5];
#pragma unroll
                for (int c = 0; c < 5; ++c)
                    bq[c] = *(const float4*)&Ws[c0 + c][k0];
#pragma unroll
                for (int c = 0; c < 5; ++c) {
                    acc[c] += a00.x * bq[c].x; acc[5 + c] += a10.x * bq[c].x;
                }
#pragma unroll
                for (int c = 0; c < 5; ++c) {
                    acc[c] += a00.y * bq[c].y; acc[5 + c] += a10.y * bq[c].y;
                }
#pragma unroll
                for (int c = 0; c < 5; ++c) {
                    acc[c] += a01.x * bq[c].z; acc[5 + c] += a11.x * bq[c].z;
                }
#pragma unroll
                for (int c = 0; c < 5; ++c) {
                    acc[c] += a01.y * bq[c].w; acc[5 + c] += a11.y * bq[c].w;
                }
            }
        } else {
            const int c0 = wave * 4;
#pragma unroll 2
            for (int kq = 0; kq < 16; ++kq) {
                const int k0 = kq * 4;
                const float2 a00 = *(const float2*)&Hs[lane][k0];
                const float2 a01 = *(const float2*)&Hs[lane][k0 + 2];
                const float2 a10 = *(const float2*)&Hs[64 + lane][k0];
                const float2 a11 = *(const float2*)&Hs[64 + lane][k0 + 2];
                float4 bq[4];
#pragma unroll
                for (int c = 0; c < 4; ++c)
                    bq[c] = *(const float4*)&Ws[c0 + c][k0];
#pragma unroll
                for (int c = 0; c < 4; ++c) {
                    acc[c] += a00.x * bq[c].x; acc[5 + c] += a10.x * bq[c].x;
                }
#pragma unroll
                for (int c = 0; c < 4; ++c) {
                    acc[c] += a00.y * bq[c].y; acc[5 + c] += a10.y * bq[c].y;
                }
#pragma unroll
                for (int c = 0; c < 4; ++c) {
                    acc[c] += a01.x * bq[c].z; acc[5 + c] += a11.x * bq[c].z;
                }
#pragma unroll
                for (int c = 0; c < 4; ++c) {
                    acc[c] += a01.y * bq[c].w; acc[5 + c] += a11.y * bq[c].w;
                }
            }
        }
        __syncthreads();
    }

    // ---- write k-half partial scores (2 tokens per lane) ----
    const int gcol = (slab ? 40 + wave * 4 : wave * 5);
    const int nout = slab ? 4 : 5;
    float* dstS  = Sp + (size_t)z * (NTOK * 72) + (size_t)(t0 + lane) * 72 + gcol;
    float* dstS2 = Sp + (size_t)z * (NTOK * 72) + (size_t)(t0 + 64 + lane) * 72 + gcol;
#pragma unroll
    for (int c = 0; c < 5; ++c) {
        if (c < nout) {
            dstS[c]  = acc[c];
            dstS2[c] = acc[5 + c];
        }
    }
}

// ---------------------------------------------------------------------------
// route_all: sum 2 k-half partials (verified order), group argmax (+bg),
// top-2 in selected group, softmax, outputs + DIRECT scatter into fixed-cap
// per-expert buckets (verified r9; intra-bucket order arbitrary — benign).
// ---------------------------------------------------------------------------
__global__ __launch_bounds__(256) void route_all(
    const float* __restrict__ Sp, const float* __restrict__ bg,
    float* __restrict__ out_gidx, float* __restrict__ out_eid,
    float* __restrict__ out_gate, int* __restrict__ cursor,
    int* __restrict__ token_list, float* __restrict__ slot_gate)
{
    const int t = blockIdx.x * 256 + threadIdx.x;
    const float* p0 = Sp + (size_t)t * 72;
    const float* p1 = p0 + (size_t)NTOK * 72;
    float s[72];
#pragma unroll
    for (int i = 0; i < 18; ++i) {
        const float4 a = *(const float4*)(p0 + i * 4);
        const float4 b = *(const float4*)(p1 + i * 4);
        s[i * 4 + 0] = a.x + b.x; s[i * 4 + 1] = a.y + b.y;
        s[i * 4 + 2] = a.z + b.z; s[i * 4 + 3] = a.w + b.w;
    }

    int gi = 0; float best = s[0] + bg[0];
#pragma unroll
    for (int g = 1; g < NGRP; ++g) {
        const float v = s[g] + bg[g];
        if (v > best) { best = v; gi = g; }
    }

    float ls[NLOC];
#pragma unroll
    for (int m = 0; m < NLOC; ++m) ls[m] = s[8 + gi * NLOC + m];

    int m1 = 0; float v1 = ls[0];
#pragma unroll
    for (int m = 1; m < NLOC; ++m) { if (ls[m] > v1) { v1 = ls[m]; m1 = m; } }
    int m2 = (m1 == 0) ? 1 : 0; float v2 = ls[m2];
#pragma unroll
    for (int m = 0; m < NLOC; ++m) {
        if (m != m1 && m != ((m1 == 0) ? 1 : 0) && ls[m] > v2) { v2 = ls[m]; m2 = m; }
    }
    const float e2v = expf(v2 - v1);
    const float inv = 1.f / (1.f + e2v);
    const float g0 = inv, g1 = e2v * inv;
    const int ea = gi * NLOC + m1, eb = gi * NLOC + m2;

    out_gidx[t] = (float)gi;
    out_eid[t * 2 + 0] = (float)ea;
    out_eid[t * 2 + 1] = (float)eb;
    out_gate[t * 2 + 0] = g0;
    out_gate[t * 2 + 1] = g1;

    const int pA = atomicAdd(&cursor[ea], 1);
    if (pA < ECAP) {
        token_list[ea * ECAP + pA] = t * 2 + 0;
        slot_gate[ea * ECAP + pA] = g0;
    }
    const int pB = atomicAdd(&cursor[eb], 1);
    if (pB < ECAP) {
        token_list[eb * ECAP + pB] = t * 2 + 1;
        slot_gate[eb * ECAP + pB] = g1;
    }
}

// ---------------------------------------------------------------------------
// prep_w: merged W1 and W2 transpose+cast. y<16 -> W1 [e][k][r] -> [e][r][k];
// y>=16 -> W2 [e][r][d] -> [e][d][r].
// ---------------------------------------------------------------------------
__global__ __launch_bounds__(256) void prep_w(
    const float* __restrict__ W1, const float* __restrict__ W2,
    unsigned short* __restrict__ W1t, unsigned short* __restrict__ W2t)
{
    __shared__ float Ls[64][65];
    const int e = blockIdx.x;
    const int y = blockIdx.y;
    if (y < 16) {
        const int kb = y;
        const float* src = W1 + (size_t)e * DIM * RANK + (size_t)kb * 64 * RANK;
#pragma unroll
        for (int it = 0; it < 4; ++it) {
            const int kk = (threadIdx.x >> 4) + it * 16;
            const int rr = (threadIdx.x & 15) * 4;
            *(float4*)&Ls[kk][rr] = *(const float4*)(src + (size_t)kk * RANK + rr);
        }
        __syncthreads();
#pragma unroll
        for (int it = 0; it < 2; ++it) {
            const int idx = threadIdx.x + it * 256;
            const int r = idx >> 3, k8 = (idx & 7) * 8;
            uint4 v;
            v.x = pack_bf16x2(Ls[k8 + 0][r], Ls[k8 + 1][r]);
            v.y = pack_bf16x2(Ls[k8 + 2][r], Ls[k8 + 3][r]);
            v.z = pack_bf16x2(Ls[k8 + 4][r], Ls[k8 + 5][r]);
            v.w = pack_bf16x2(Ls[k8 + 6][r], Ls[k8 + 7][r]);
            *(uint4*)(W1t + (size_t)e * RANK * DIM + (size_t)r * DIM + kb * 64 + k8) = v;
        }
    } else {
        const int db = y - 16;
        const float* src = W2 + (size_t)e * RANK * DIM + db * 64;
#pragma unroll
        for (int it = 0; it < 4; ++it) {
            const int rr = (threadIdx.x >> 4) + it * 16;
            const int dd = (threadIdx.x & 15) * 4;
            *(float4*)&Ls[rr][dd] = *(const float4*)(src + (size_t)rr * DIM + dd);
        }
        __syncthreads();
#pragma unroll
        for (int it = 0; it < 2; ++it) {
            const int idx = threadIdx.x + it * 256;
            const int d = idx >> 3, r8 = (idx & 7) * 8;
            uint4 v;
            v.x = pack_bf16x2(Ls[r8 + 0][d], Ls[r8 + 1][d]);
            v.y = pack_bf16x2(Ls[r8 + 2][d], Ls[r8 + 3][d]);
            v.z = pack_bf16x2(Ls[r8 + 4][d], Ls[r8 + 5][d]);
            v.w = pack_bf16x2(Ls[r8 + 6][d], Ls[r8 + 7][d]);
            *(uint4*)(W2t + (size_t)e * DIM * RANK + (size_t)(db * 64 + d) * RANK + r8) = v;
        }
    }
}

// ---------------------------------------------------------------------------
// E12 (fused MFMA): per 64-slot tile, compute P = bf16(gate*relu(h@W1)) into
// LDS, then immediately P@W2 for all 16 col-blocks. Removes the P global
// round-trip, e2's P staging, and one dispatch boundary. Arithmetic sequence
// (bf16 quantization point, MFMA order, ent&1 out/contrib split) identical
// to the verified e1+e2 path -> bitwise-identical output.
// NOTE: hb must NOT alias contrib here (this kernel reads hb and writes
// contrib concurrently across blocks) — hb has its own ws slot.
// ---------------------------------------------------------------------------
__global__ __launch_bounds__(256, 2) void e12_mfma(
    const unsigned short* __restrict__ hb, const unsigned short* __restrict__ W1t,
    const unsigned short* __restrict__ W2t, const int* __restrict__ counts,
    const int* __restrict__ token_list, const float* __restrict__ slot_gate,
    float* __restrict__ out, float* __restrict__ contrib)
{
    __shared__ unsigned short Hs[64 * 72];
    __shared__ unsigned short Ws[64 * 72];
    __shared__ unsigned short Ps[64 * 72];
    __shared__ unsigned short W2s[64 * 72];
    __shared__ int   tokS[64];
    __shared__ float gateS[64];

    const int e    = blockIdx.x;
    const int tid  = threadIdx.x;
    const int ne   = min(counts[e], ECAP);
    const int base = e * ECAP;

    const unsigned short* W1te = W1t + (size_t)e * RANK * DIM;
    const unsigned short* W2te = W2t + (size_t)e * DIM * RANK;
    const int wave = tid >> 6;
    const int lane = tid & 63;
    const int tx   = lane & 15;
    const int quad = lane >> 4;

    for (int tile = blockIdx.y; tile * 64 < ne; tile += 8) {
        const int row0 = tile * 64;
        __syncthreads();   // prev tile's Ps/W2s/tokS readers done
        if (tid < 64) {
            const int gr = row0 + tid;
            tokS[tid]  = (gr < ne) ? token_list[base + gr] : -1;
            gateS[tid] = (gr < ne) ? slot_gate[base + gr] : 0.f;
        }

        // ---- stage 1: h @ W1 over K=1024 ----
        f32x4 acc[4] = {};
        for (int kc = 0; kc < DIM; kc += 64) {
            __syncthreads();   // tokS ready (1st) / prev kc reads done
#pragma unroll
            for (int it = 0; it < 2; ++it) {
                const int idx = tid + it * 256;
                const int s = idx >> 3, k8 = (idx & 7) * 8;
                const int ent = tokS[s];
                uint4 v = make_uint4(0, 0, 0, 0);
                if (ent >= 0)
                    v = *(const uint4*)(hb + (size_t)(ent >> 1) * DIM + kc + k8);
                *(uint4*)(Hs + s * 72 + k8) = v;
            }
#pragma unroll
            for (int it = 0; it < 2; ++it) {
                const int idx = tid + it * 256;
                const int r = idx >> 3, k8 = (idx & 7) * 8;
                *(uint4*)(Ws + r * 72 + k8) =
                    *(const uint4*)(W1te + (size_t)r * DIM + kc + k8);
            }
            __syncthreads();
#pragma unroll
            for (int ks = 0; ks < 2; ++ks) {
                const bf16x8 a = *(const bf16x8*)(Hs + (wave * 16 + tx) * 72 + ks * 32 + quad * 8);
#pragma unroll
                for (int j = 0; j < 4; ++j) {
                    const bf16x8 b = *(const bf16x8*)(Ws + (j * 16 + tx) * 72 + ks * 32 + quad * 8);
                    acc[j] = __builtin_amdgcn_mfma_f32_16x16x32_bf16(a, b, acc[j], 0, 0, 0);
                }
            }
        }

        // ---- P = bf16(gate * relu(acc)) -> LDS (same quantization as e1) ----
#pragma unroll
        for (int j = 0; j < 4; ++j) {
#pragma unroll
            for (int i = 0; i < 4; ++i) {
                const int sl = wave * 16 + quad * 4 + i;
                const float v = fmaxf(acc[j][i], 0.f) * gateS[sl];
                __hip_bfloat16 hv = __float2bfloat16(v);
                Ps[sl * 72 + j * 16 + tx] = *(unsigned short*)&hv;
            }
        }
        __syncthreads();   // Ps complete

        // ---- stage 2: P @ W2 for all 16 col-blocks ----
        for (int cb = 0; cb < 16; ++cb) {
            const int colbase = cb * 64;
#pragma unroll
            for (int it = 0; it < 2; ++it) {
                const int idx = tid + it * 256;
                const int d = idx >> 3, r8 = (idx & 7) * 8;
                *(uint4*)(W2s + d * 72 + r8) =
                    *(const uint4*)(W2te + (size_t)(colbase + d) * RANK + r8);
            }
            __syncthreads();
            f32x4 acc2[4] = {};
#pragma unroll
            for (int ks = 0; ks < 2; ++ks) {
                const bf16x8 a = *(const bf16x8*)(Ps + (wave * 16 + tx) * 72 + ks * 32 + quad * 8);
#pragma unroll
                for (int j = 0; j < 4; ++j) {
                    const bf16x8 b = *(const bf16x8*)(W2s + (j * 16 + tx) * 72 + ks * 32 + quad * 8);
                    acc2[j] = __builtin_amdgcn_mfma_f32_16x16x32_bf16(a, b, acc2[j], 0, 0, 0);
                }
            }
#pragma unroll
            for (int i = 0; i < 4; ++i) {
                const int sl = wave * 16 + quad * 4 + i;
                const int ent = tokS[sl];
                if (ent >= 0) {
                    float* basep = (ent & 1) ? contrib : out;
                    float* op = basep + (size_t)(ent >> 1) * DIM + colbase;
#pragma unroll
                    for (int j = 0; j < 4; ++j)
                        op[j * 16 + tx] = acc2[j][i];
                }
            }
            __syncthreads();   // W2s reads done before next cb overwrites
        }
    }
}

// ---------------------------------------------------------------------------
__global__ __launch_bounds__(256) void combine_kernel(
    const float* __restrict__ contrib, float* __restrict__ out)
{
    const size_t i = (size_t)blockIdx.x * 256 + threadIdx.x;
    float4 a = ((const float4*)out)[i];
    const float4 b = ((const float4*)contrib)[i];
    a.x += b.x; a.y += b.y; a.z += b.z; a.w += b.w;
    ((float4*)out)[i] = a;
}

// ---------------------------------------------------------------------------
extern "C" void kernel_launch(void* const* d_in, const int* in_sizes, int n_in,
                              void* d_out, int out_size, void* d_ws, size_t ws_size,
                              hipStream_t stream)
{
    const float* h    = (const float*)d_in[0];
    const float* Wg   = (const float*)d_in[1];
    const float* bg   = (const float*)d_in[2];
    const float* Wloc = (const float*)d_in[3];
    const float* W1   = (const float*)d_in[4];
    const float* W2   = (const float*)d_in[5];

    float* out_f    = (float*)d_out;
    float* out_main = out_f;
    float* out_eid  = out_f + (size_t)NTOK * DIM;
    float* out_gate = out_eid + (size_t)NTOK * 2;
    float* out_gidx = out_gate + (size_t)NTOK * 2;

    int* ws_i        = (int*)d_ws;
    int* cursor_e    = ws_i;                                  // 64 ints
    int* token_list  = ws_i + 1024;                           // 64*2048 ints
    float* slot_gate = (float*)(ws_i + 1024 + NEXP * ECAP);   // 64*2048 floats
    float* Sp        = slot_gate + NEXP * ECAP;               // 2*8192*72 floats
    unsigned short* hb  = (unsigned short*)(Sp + (size_t)2 * NTOK * 72);  // 16.8 MB
    unsigned short* W1t = hb + (size_t)NTOK * DIM;            // 8 MB
    unsigned short* W2t = W1t + (size_t)NEXP * RANK * DIM;    // 8 MB
    float* contrib      = (float*)(W2t + (size_t)NEXP * DIM * RANK);  // 33.5 MB
    // hb does NOT alias contrib (e12 reads hb while writing contrib).

    hipMemsetAsync(cursor_e, 0, 64 * sizeof(int), stream);

    prep_w<<<dim3(NEXP, 32), 256, 0, stream>>>(W1, W2, W1t, W2t);
    score_all<<<dim3(64, 2, 2), 512, 0, stream>>>(h, Wg, Wloc, hb, Sp);
    route_all<<<NTOK / 256, 256, 0, stream>>>(Sp, bg, out_gidx, out_eid,
        out_gate, cursor_e, token_list, slot_gate);
    e12_mfma<<<dim3(NEXP, 8), 256, 0, stream>>>(hb, W1t, W2t, cursor_e,
        token_list, slot_gate, out_main, contrib);
    combine_kernel<<<(NTOK * DIM / 4) / 256, 256, 0, stream>>>(contrib, out_main);
}

// Round 11
// 235.949 us; speedup vs baseline: 1.1293x; 1.0138x over previous
//
#include <hip/hip_runtime.h>
#include <hip/hip_bf16.h>
#include <cstdint>
#include <cstddef>

#define NTOK 8192
#define DIM  1024
#define NEXP 64
#define RANK 64
#define NGRP 8
#define NLOC 8
#define ECAP 2048   // per-expert bucket capacity (expected ~256, 8x margin)

typedef __attribute__((ext_vector_type(8))) short bf16x8;
typedef __attribute__((ext_vector_type(4))) float f32x4;

static __device__ inline unsigned int pack_bf16x2(float a, float b) {
    __hip_bfloat16 ha = __float2bfloat16(a);
    __hip_bfloat16 hb = __float2bfloat16(b);
    return (unsigned int)(*(unsigned short*)&ha) |
           ((unsigned int)(*(unsigned short*)&hb) << 16);
}

// ---------------------------------------------------------------------------
// score_all: dense fp32 GEMM  S[8192][72] = h @ [Wg | Wloc_g0..g7].
// FP-ORDER CONTRACT (round-5 failure): per token+column, accumulation is
// serial over k ascending within each k-half (z=2); halves added pairwise in
// route_all — EXACTLY the verified order. Per-token-column FMA chains here
// are bitwise identical to rounds 8/10 (dropping the 2nd token per lane
// removes independent chains only).
// Round-10 post-mortem: 50us at Occupancy 17% = 1 block/CU (grid 256 = CU
// count); latency+barrier bound — both pipes ~2.5x underutilized, LDS only
// 45KB/160KB. Fix: 64-token tiles -> grid 512 = 2 blocks/CU (16 waves);
// during one block's barrier drain the other issues. LDS 28.4 KB/block.
// ---------------------------------------------------------------------------
__global__ __launch_bounds__(512) void score_all(
    const float* __restrict__ h, const float* __restrict__ Wg,
    const float* __restrict__ Wloc, unsigned short* __restrict__ hb,
    float* __restrict__ Sp)
{
    __shared__ float Hs[64][66];   // [token][k], pad 66
    __shared__ float Ws[40][72];   // [col][k],  pad 72: uniform b128 broadcast

    const int tile = blockIdx.x;          // 0..127 (64 tokens)
    const int slab = blockIdx.y;          // 0: cols 0..39 (Wg,g0..3)  1: 40..71 (g4..7)
    const int z    = blockIdx.z;          // k half (ORDER-LOCKED: must stay 2)
    const int tid  = threadIdx.x;
    const int wave = tid >> 6;            // 0..7
    const int lane = tid & 63;
    const int t0   = tile * 64;
    const int kz   = z * 512;

    const int r0  = tid >> 3;             // 0..63 (staging row)
    const int seg = (tid & 7) * 8;        // 0,8,...,56

    float acc[5] = {};

    float4 hpre[2];
    float4 wgp;          // slab 0, tid<128 only
    float4 wlp;

    {   // prologue: load chunk 0
        const int kb = kz;
        const float* src = h + (size_t)(t0 + r0) * DIM + kb + seg;
        hpre[0] = *(const float4*)(src);
        hpre[1] = *(const float4*)(src + 4);
        const int g = tid >> 7, r = tid & 127;
        if (slab == 0) {
            if (tid < 128)
                wgp = *(const float4*)(Wg + (size_t)(kb + (tid >> 1)) * NGRP + (tid & 1) * 4);
            wlp = *(const float4*)(Wloc + (size_t)g * (DIM * NLOC)
                                       + (size_t)(kb + (r >> 1)) * NLOC + (r & 1) * 4);
        } else {
            wlp = *(const float4*)(Wloc + (size_t)(4 + g) * (DIM * NLOC)
                                       + (size_t)(kb + (r >> 1)) * NLOC + (r & 1) * 4);
        }
    }

    for (int chunk = 0; chunk < 8; ++chunk) {
        const int kb = kz + chunk * 64;

        // ---- write staged regs -> LDS (+ fused hb cast on slab 0) ----
        {
            float* dst = &Hs[r0][seg];
#pragma unroll
            for (int q = 0; q < 2; ++q) {
                const float4 v = hpre[q];
                *(float2*)(dst + q * 4)     = make_float2(v.x, v.y);
                *(float2*)(dst + q * 4 + 2) = make_float2(v.z, v.w);
            }
            if (slab == 0) {
                unsigned short* hrow = hb + (size_t)(t0 + r0) * DIM + kb + seg;
#pragma unroll
                for (int q = 0; q < 2; ++q) {
                    const float4 v = hpre[q];
                    uint2 pk;
                    pk.x = pack_bf16x2(v.x, v.y);
                    pk.y = pack_bf16x2(v.z, v.w);
                    *(uint2*)(hrow + q * 4) = pk;
                }
            }
        }
        {
            const int g = tid >> 7, r = tid & 127;
            const int k = r >> 1;
            if (slab == 0) {
                if (tid < 128) {
                    const int kk = tid >> 1, m4 = (tid & 1) * 4;
                    Ws[m4 + 0][kk] = wgp.x; Ws[m4 + 1][kk] = wgp.y;
                    Ws[m4 + 2][kk] = wgp.z; Ws[m4 + 3][kk] = wgp.w;
                }
                const int c = 8 + g * 8 + (r & 1) * 4;
                Ws[c + 0][k] = wlp.x; Ws[c + 1][k] = wlp.y;
                Ws[c + 2][k] = wlp.z; Ws[c + 3][k] = wlp.w;
            } else {
                const int c = g * 8 + (r & 1) * 4;
                Ws[c + 0][k] = wlp.x; Ws[c + 1][k] = wlp.y;
                Ws[c + 2][k] = wlp.z; Ws[c + 3][k] = wlp.w;
            }
        }
        __syncthreads();

        // ---- prefetch chunk+1 (global loads overlap compute below) ----
        if (chunk < 7) {
            const int kbn = kb + 64;
            const float* src = h + (size_t)(t0 + r0) * DIM + kbn + seg;
            hpre[0] = *(const float4*)(src);
            hpre[1] = *(const float4*)(src + 4);
            const int g = tid >> 7, r = tid & 127;
            if (slab == 0) {
                if (tid < 128)
                    wgp = *(const float4*)(Wg + (size_t)(kbn + (tid >> 1)) * NGRP + (tid & 1) * 4);
                wlp = *(const float4*)(Wloc + (size_t)g * (DIM * NLOC)
                                           + (size_t)(kbn + (r >> 1)) * NLOC + (r & 1) * 4);
            } else {
                wlp = *(const float4*)(Wloc + (size_t)(4 + g) * (DIM * NLOC)
                                           + (size_t)(kbn + (r >> 1)) * NLOC + (r & 1) * 4);
            }
        }

        // ---- compute: lane = token t0+lane, wave = col block ----
        // Per acc[c]: k strictly ascending (x,y,z,w per quad) == verified order.
        if (slab == 0) {
            const int c0 = wave * 5;
#pragma unroll 4
            for (int kq = 0; kq < 16; ++kq) {
                const int k0 = kq * 4;
                const float2 a00 = *(const float2*)&Hs[lane][k0];
                const float2 a01 = *(const float2*)&Hs[lane][k0 + 2];
                float4 bq[5];
#pragma unroll
                for (int c = 0; c < 5; ++c)
                    bq[c] = *(const float4*)&Ws[c0 + c][k0];
#pragma unroll
                for (int c = 0; c < 5; ++c) acc[c] += a00.x * bq[c].x;
#pragma unroll
                for (int c = 0; c < 5; ++c) acc[c] += a00.y * bq[c].y;
#pragma unroll
                for (int c = 0; c < 5; ++c) acc[c] += a01.x * bq[c].z;
#pragma unroll
                for (int c = 0; c < 5; ++c) acc[c] += a01.y * bq[c].w;
            }
        } else {
            const int c0 = wave * 4;
#pragma unroll 4
            for (int kq = 0; kq < 16; ++kq) {
                const int k0 = kq * 4;
                const float2 a00 = *(const float2*)&Hs[lane][k0];
                const float2 a01 = *(const float2*)&Hs[lane][k0 + 2];
                float4 bq[4];
#pragma unroll
                for (int c = 0; c < 4; ++c)
                    bq[c] = *(const float4*)&Ws[c0 + c][k0];
#pragma unroll
                for (int c = 0; c < 4; ++c) acc[c] += a00.x * bq[c].x;
#pragma unroll
                for (int c = 0; c < 4; ++c) acc[c] += a00.y * bq[c].y;
#pragma unroll
                for (int c = 0; c < 4; ++c) acc[c] += a01.x * bq[c].z;
#pragma unroll
                for (int c = 0; c < 4; ++c) acc[c] += a01.y * bq[c].w;
            }
        }
        __syncthreads();
    }

    // ---- write k-half partial scores (1 token per lane) ----
    const int gcol = (slab ? 40 + wave * 4 : wave * 5);
    const int nout = slab ? 4 : 5;
    float* dstS = Sp + (size_t)z * (NTOK * 72) + (size_t)(t0 + lane) * 72 + gcol;
#pragma unroll
    for (int c = 0; c < 5; ++c)
        if (c < nout) dstS[c] = acc[c];
}

// ---------------------------------------------------------------------------
// route_all: sum 2 k-half partials (verified order), group argmax (+bg),
// top-2 in selected group, softmax, outputs + DIRECT scatter into fixed-cap
// per-expert buckets (verified r9/r10; intra-bucket order arbitrary).
// ---------------------------------------------------------------------------
__global__ __launch_bounds__(256) void route_all(
    const float* __restrict__ Sp, const float* __restrict__ bg,
    float* __restrict__ out_gidx, float* __restrict__ out_eid,
    float* __restrict__ out_gate, int* __restrict__ cursor,
    int* __restrict__ token_list, float* __restrict__ slot_gate)
{
    const int t = blockIdx.x * 256 + threadIdx.x;
    const float* p0 = Sp + (size_t)t * 72;
    const float* p1 = p0 + (size_t)NTOK * 72;
    float s[72];
#pragma unroll
    for (int i = 0; i < 18; ++i) {
        const float4 a = *(const float4*)(p0 + i * 4);
        const float4 b = *(const float4*)(p1 + i * 4);
        s[i * 4 + 0] = a.x + b.x; s[i * 4 + 1] = a.y + b.y;
        s[i * 4 + 2] = a.z + b.z; s[i * 4 + 3] = a.w + b.w;
    }

    int gi = 0; float best = s[0] + bg[0];
#pragma unroll
    for (int g = 1; g < NGRP; ++g) {
        const float v = s[g] + bg[g];
        if (v > best) { best = v; gi = g; }
    }

    float ls[NLOC];
#pragma unroll
    for (int m = 0; m < NLOC; ++m) ls[m] = s[8 + gi * NLOC + m];

    int m1 = 0; float v1 = ls[0];
#pragma unroll
    for (int m = 1; m < NLOC; ++m) { if (ls[m] > v1) { v1 = ls[m]; m1 = m; } }
    int m2 = (m1 == 0) ? 1 : 0; float v2 = ls[m2];
#pragma unroll
    for (int m = 0; m < NLOC; ++m) {
        if (m != m1 && m != ((m1 == 0) ? 1 : 0) && ls[m] > v2) { v2 = ls[m]; m2 = m; }
    }
    const float e2v = expf(v2 - v1);
    const float inv = 1.f / (1.f + e2v);
    const float g0 = inv, g1 = e2v * inv;
    const int ea = gi * NLOC + m1, eb = gi * NLOC + m2;

    out_gidx[t] = (float)gi;
    out_eid[t * 2 + 0] = (float)ea;
    out_eid[t * 2 + 1] = (float)eb;
    out_gate[t * 2 + 0] = g0;
    out_gate[t * 2 + 1] = g1;

    const int pA = atomicAdd(&cursor[ea], 1);
    if (pA < ECAP) {
        token_list[ea * ECAP + pA] = t * 2 + 0;
        slot_gate[ea * ECAP + pA] = g0;
    }
    const int pB = atomicAdd(&cursor[eb], 1);
    if (pB < ECAP) {
        token_list[eb * ECAP + pB] = t * 2 + 1;
        slot_gate[eb * ECAP + pB] = g1;
    }
}

// ---------------------------------------------------------------------------
// prep_w: merged W1 and W2 transpose+cast. y<16 -> W1 [e][k][r] -> [e][r][k];
// y>=16 -> W2 [e][r][d] -> [e][d][r].
// ---------------------------------------------------------------------------
__global__ __launch_bounds__(256) void prep_w(
    const float* __restrict__ W1, const float* __restrict__ W2,
    unsigned short* __restrict__ W1t, unsigned short* __restrict__ W2t)
{
    __shared__ float Ls[64][65];
    const int e = blockIdx.x;
    const int y = blockIdx.y;
    if (y < 16) {
        const int kb = y;
        const float* src = W1 + (size_t)e * DIM * RANK + (size_t)kb * 64 * RANK;
#pragma unroll
        for (int it = 0; it < 4; ++it) {
            const int kk = (threadIdx.x >> 4) + it * 16;
            const int rr = (threadIdx.x & 15) * 4;
            *(float4*)&Ls[kk][rr] = *(const float4*)(src + (size_t)kk * RANK + rr);
        }
        __syncthreads();
#pragma unroll
        for (int it = 0; it < 2; ++it) {
            const int idx = threadIdx.x + it * 256;
            const int r = idx >> 3, k8 = (idx & 7) * 8;
            uint4 v;
            v.x = pack_bf16x2(Ls[k8 + 0][r], Ls[k8 + 1][r]);
            v.y = pack_bf16x2(Ls[k8 + 2][r], Ls[k8 + 3][r]);
            v.z = pack_bf16x2(Ls[k8 + 4][r], Ls[k8 + 5][r]);
            v.w = pack_bf16x2(Ls[k8 + 6][r], Ls[k8 + 7][r]);
            *(uint4*)(W1t + (size_t)e * RANK * DIM + (size_t)r * DIM + kb * 64 + k8) = v;
        }
    } else {
        const int db = y - 16;
        const float* src = W2 + (size_t)e * RANK * DIM + db * 64;
#pragma unroll
        for (int it = 0; it < 4; ++it) {
            const int rr = (threadIdx.x >> 4) + it * 16;
            const int dd = (threadIdx.x & 15) * 4;
            *(float4*)&Ls[rr][dd] = *(const float4*)(src + (size_t)rr * DIM + dd);
        }
        __syncthreads();
#pragma unroll
        for (int it = 0; it < 2; ++it) {
            const int idx = threadIdx.x + it * 256;
            const int d = idx >> 3, r8 = (idx & 7) * 8;
            uint4 v;
            v.x = pack_bf16x2(Ls[r8 + 0][d], Ls[r8 + 1][d]);
            v.y = pack_bf16x2(Ls[r8 + 2][d], Ls[r8 + 3][d]);
            v.z = pack_bf16x2(Ls[r8 + 4][d], Ls[r8 + 5][d]);
            v.w = pack_bf16x2(Ls[r8 + 6][d], Ls[r8 + 7][d]);
            *(uint4*)(W2t + (size_t)e * DIM * RANK + (size_t)(db * 64 + d) * RANK + r8) = v;
        }
    }
}

// ---------------------------------------------------------------------------
// E12 (fused MFMA, verified r10): per 64-slot tile, P = bf16(gate*relu(h@W1))
// into LDS, then immediately P@W2 for all 16 col-blocks. hb must NOT alias
// contrib (reads hb while writing contrib).
// ---------------------------------------------------------------------------
__global__ __launch_bounds__(256, 2) void e12_mfma(
    const unsigned short* __restrict__ hb, const unsigned short* __restrict__ W1t,
    const unsigned short* __restrict__ W2t, const int* __restrict__ counts,
    const int* __restrict__ token_list, const float* __restrict__ slot_gate,
    float* __restrict__ out, float* __restrict__ contrib)
{
    __shared__ unsigned short Hs[64 * 72];
    __shared__ unsigned short Ws[64 * 72];
    __shared__ unsigned short Ps[64 * 72];
    __shared__ unsigned short W2s[64 * 72];
    __shared__ int   tokS[64];
    __shared__ float gateS[64];

    const int e    = blockIdx.x;
    const int tid  = threadIdx.x;
    const int ne   = min(counts[e], ECAP);
    const int base = e * ECAP;

    const unsigned short* W1te = W1t + (size_t)e * RANK * DIM;
    const unsigned short* W2te = W2t + (size_t)e * DIM * RANK;
    const int wave = tid >> 6;
    const int lane = tid & 63;
    const int tx   = lane & 15;
    const int quad = lane >> 4;

    for (int tile = blockIdx.y; tile * 64 < ne; tile += 8) {
        const int row0 = tile * 64;
        __syncthreads();   // prev tile's Ps/W2s/tokS readers done
        if (tid < 64) {
            const int gr = row0 + tid;
            tokS[tid]  = (gr < ne) ? token_list[base + gr] : -1;
            gateS[tid] = (gr < ne) ? slot_gate[base + gr] : 0.f;
        }

        // ---- stage 1: h @ W1 over K=1024 ----
        f32x4 acc[4] = {};
        for (int kc = 0; kc < DIM; kc += 64) {
            __syncthreads();   // tokS ready (1st) / prev kc reads done
#pragma unroll
            for (int it = 0; it < 2; ++it) {
                const int idx = tid + it * 256;
                const int s = idx >> 3, k8 = (idx & 7) * 8;
                const int ent = tokS[s];
                uint4 v = make_uint4(0, 0, 0, 0);
                if (ent >= 0)
                    v = *(const uint4*)(hb + (size_t)(ent >> 1) * DIM + kc + k8);
                *(uint4*)(Hs + s * 72 + k8) = v;
            }
#pragma unroll
            for (int it = 0; it < 2; ++it) {
                const int idx = tid + it * 256;
                const int r = idx >> 3, k8 = (idx & 7) * 8;
                *(uint4*)(Ws + r * 72 + k8) =
                    *(const uint4*)(W1te + (size_t)r * DIM + kc + k8);
            }
            __syncthreads();
#pragma unroll
            for (int ks = 0; ks < 2; ++ks) {
                const bf16x8 a = *(const bf16x8*)(Hs + (wave * 16 + tx) * 72 + ks * 32 + quad * 8);
#pragma unroll
                for (int j = 0; j < 4; ++j) {
                    const bf16x8 b = *(const bf16x8*)(Ws + (j * 16 + tx) * 72 + ks * 32 + quad * 8);
                    acc[j] = __builtin_amdgcn_mfma_f32_16x16x32_bf16(a, b, acc[j], 0, 0, 0);
                }
            }
        }

        // ---- P = bf16(gate * relu(acc)) -> LDS (same quantization as e1) ----
#pragma unroll
        for (int j = 0; j < 4; ++j) {
#pragma unroll
            for (int i = 0; i < 4; ++i) {
                const int sl = wave * 16 + quad * 4 + i;
                const float v = fmaxf(acc[j][i], 0.f) * gateS[sl];
                __hip_bfloat16 hv = __float2bfloat16(v);
                Ps[sl * 72 + j * 16 + tx] = *(unsigned short*)&hv;
            }
        }
        __syncthreads();   // Ps complete

        // ---- stage 2: P @ W2 for all 16 col-blocks ----
        for (int cb = 0; cb < 16; ++cb) {
            const int colbase = cb * 64;
#pragma unroll
            for (int it = 0; it < 2; ++it) {
                const int idx = tid + it * 256;
                const int d = idx >> 3, r8 = (idx & 7) * 8;
                *(uint4*)(W2s + d * 72 + r8) =
                    *(const uint4*)(W2te + (size_t)(colbase + d) * RANK + r8);
            }
            __syncthreads();
            f32x4 acc2[4] = {};
#pragma unroll
            for (int ks = 0; ks < 2; ++ks) {
                const bf16x8 a = *(const bf16x8*)(Ps + (wave * 16 + tx) * 72 + ks * 32 + quad * 8);
#pragma unroll
                for (int j = 0; j < 4; ++j) {
                    const bf16x8 b = *(const bf16x8*)(W2s + (j * 16 + tx) * 72 + ks * 32 + quad * 8);
                    acc2[j] = __builtin_amdgcn_mfma_f32_16x16x32_bf16(a, b, acc2[j], 0, 0, 0);
                }
            }
#pragma unroll
            for (int i = 0; i < 4; ++i) {
                const int sl = wave * 16 + quad * 4 + i;
                const int ent = tokS[sl];
                if (ent >= 0) {
                    float* basep = (ent & 1) ? contrib : out;
                    float* op = basep + (size_t)(ent >> 1) * DIM + colbase;
#pragma unroll
                    for (int j = 0; j < 4; ++j)
                        op[j * 16 + tx] = acc2[j][i];
                }
            }
            __syncthreads();   // W2s reads done before next cb overwrites
        }
    }
}

// ---------------------------------------------------------------------------
__global__ __launch_bounds__(256) void combine_kernel(
    const float* __restrict__ contrib, float* __restrict__ out)
{
    const size_t i = (size_t)blockIdx.x * 256 + threadIdx.x;
    float4 a = ((const float4*)out)[i];
    const float4 b = ((const float4*)contrib)[i];
    a.x += b.x; a.y += b.y; a.z += b.z; a.w += b.w;
    ((float4*)out)[i] = a;
}

// ---------------------------------------------------------------------------
extern "C" void kernel_launch(void* const* d_in, const int* in_sizes, int n_in,
                              void* d_out, int out_size, void* d_ws, size_t ws_size,
                              hipStream_t stream)
{
    const float* h    = (const float*)d_in[0];
    const float* Wg   = (const float*)d_in[1];
    const float* bg   = (const float*)d_in[2];
    const float* Wloc = (const float*)d_in[3];
    const float* W1   = (const float*)d_in[4];
    const float* W2   = (const float*)d_in[5];

    float* out_f    = (float*)d_out;
    float* out_main = out_f;
    float* out_eid  = out_f + (size_t)NTOK * DIM;
    float* out_gate = out_eid + (size_t)NTOK * 2;
    float* out_gidx = out_gate + (size_t)NTOK * 2;

    int* ws_i        = (int*)d_ws;
    int* cursor_e    = ws_i;                                  // 64 ints
    int* token_list  = ws_i + 1024;                           // 64*2048 ints
    float* slot_gate = (float*)(ws_i + 1024 + NEXP * ECAP);   // 64*2048 floats
    float* Sp        = slot_gate + NEXP * ECAP;               // 2*8192*72 floats
    unsigned short* hb  = (unsigned short*)(Sp + (size_t)2 * NTOK * 72);  // 16.8 MB
    unsigned short* W1t = hb + (size_t)NTOK * DIM;            // 8 MB
    unsigned short* W2t = W1t + (size_t)NEXP * RANK * DIM;    // 8 MB
    float* contrib      = (float*)(W2t + (size_t)NEXP * DIM * RANK);  // 33.5 MB
    // hb does NOT alias contrib (e12 reads hb while writing contrib).

    hipMemsetAsync(cursor_e, 0, 64 * sizeof(int), stream);

    prep_w<<<dim3(NEXP, 32), 256, 0, stream>>>(W1, W2, W1t, W2t);
    score_all<<<dim3(128, 2, 2), 512, 0, stream>>>(h, Wg, Wloc, hb, Sp);
    route_all<<<NTOK / 256, 256, 0, stream>>>(Sp, bg, out_gidx, out_eid,
        out_gate, cursor_e, token_list, slot_gate);
    e12_mfma<<<dim3(NEXP, 8), 256, 0, stream>>>(hb, W1t, W2t, cursor_e,
        token_list, slot_gate, out_main, contrib);
    combine_kernel<<<(NTOK * DIM / 4) / 256, 256, 0, stream>>>(contrib, out_main);
}